// Round 1
// baseline (360.922 us; speedup 1.0000x reference)
//
#include <hip/hip_runtime.h>
#include <hip/hip_bf16.h>
#include <cstdint>

#define DI __device__ __forceinline__

typedef short bf16x8 __attribute__((ext_vector_type(8)));     // 8 bf16 operand frag
typedef float f32x4 __attribute__((ext_vector_type(4)));      // accumulator frag
typedef unsigned short u16;
typedef unsigned short u16x8 __attribute__((ext_vector_type(8)));

static constexpr int BB = 32, TT = 64, NV = 10, HID = 256, NE = 90;
static constexpr int R1 = BB * NV * TT;   // 20480 node rows
static constexpr int R2 = BB * NE * TT;   // 184320 edge rows

DI float bf2f(u16 u) {
    union { unsigned int i; float f; } x; x.i = ((unsigned int)u) << 16; return x.f;
}
DI u16 f2bf(float f) {
    unsigned int u = __float_as_uint(f);
    unsigned int r = (u + 0x7FFF + ((u >> 16) & 1)) >> 16;
    return (u16)r;
}
DI float elu(float v) { return v > 0.f ? v : __expf(v) - 1.f; }

// -------------------- weight convert + transpose: [K,N] f32 -> [N,K] bf16 ---
__global__ __launch_bounds__(256) void transpose_w(const float* __restrict__ src,
                                                   u16* __restrict__ dst, int K, int N) {
    int idx = blockIdx.x * 256 + threadIdx.x;
    if (idx >= K * N) return;
    int k = idx / N, n = idx - k * N;
    dst[(size_t)n * K + k] = f2bf(src[idx]);
}

__global__ void zero_stats(float* p, int n) {
    int i = blockIdx.x * 256 + threadIdx.x;
    if (i < n) p[i] = 0.f;
}

// -------------------- mlp1 fc1: K=4, VALU --------------------
__global__ __launch_bounds__(256) void mlp1_fc1(const float* __restrict__ x,
                                                const float* __restrict__ w1a,
                                                const float* __restrict__ b1a,
                                                u16* __restrict__ ha) {
    int tid = threadIdx.x;
    int row = blockIdx.x * 8 + (tid >> 5);          // node row (b*NV+v)*TT+t
    int ch8 = (tid & 31) * 8;
    int b = row / (NV * TT);
    int v = (row >> 6) % NV;
    int t = row & 63;
    const float* xp = x + ((size_t)(b * TT + t) * NV + v) * 4;
    float x0 = xp[0], x1 = xp[1], x2 = xp[2], x3 = xp[3];
    u16x8 pack;
#pragma unroll
    for (int e = 0; e < 8; ++e) {
        int c = ch8 + e;
        float acc = b1a[c] + x0 * w1a[c] + x1 * w1a[256 + c] + x2 * w1a[512 + c] + x3 * w1a[768 + c];
        pack[e] = f2bf(elu(acc));
    }
    *(u16x8*)(ha + (size_t)row * 256 + ch8) = pack;
}

// -------------------- generic 128x128 bf16 MFMA GEMM --------------------
// C[M,256] = act(A[M,K] @ W[K,256] + bias), W given transposed as Wt[256,K].
// GATHER: A rows are node2edge concat rows pulled from h1n [R1,256].
template <bool GATHER, int ACT>   // ACT: 0 none, 1 elu, 2 relu
__global__ __launch_bounds__(256) void gemm_kernel(const u16* __restrict__ A,
                                                   const u16* __restrict__ Wt,
                                                   const float* __restrict__ bias,
                                                   u16* __restrict__ out,
                                                   int K) {
    __shared__ u16 As[128 * 32];
    __shared__ u16 Bs[128 * 32];
    const int tid = threadIdx.x;
    const int lane = tid & 63, wid = tid >> 6;
    const int bm = blockIdx.x >> 1, bn = blockIdx.x & 1;
    const int m0 = bm * 128, n0 = bn * 128;
    const int wm = wid >> 1, wn = wid & 1;

    const int srow = tid >> 2;           // 0..63 staging row
    const int scol8 = (tid & 3) * 8;     // k-chunk within BK

    size_t abase[2], bbase[2], sb[2], rb[2];
    if constexpr (GATHER) {
#pragma unroll
        for (int p = 0; p < 2; ++p) {
            int m = m0 + srow + p * 64;        // edge row
            int t = m & 63;
            int be = m >> 6;
            int e = be % NE;
            int b = be / NE;
            int s = e / 9;
            int kk = e - s * 9;
            int r = kk + (kk >= s ? 1 : 0);
            sb[p] = ((size_t)((b * NV + s) * TT + t)) * 256;
            rb[p] = ((size_t)((b * NV + r) * TT + t)) * 256;
        }
    } else {
#pragma unroll
        for (int p = 0; p < 2; ++p) abase[p] = (size_t)(m0 + srow + p * 64) * K;
    }
#pragma unroll
    for (int p = 0; p < 2; ++p) bbase[p] = (size_t)(n0 + srow + p * 64) * K;

    f32x4 acc[4][4];
#pragma unroll
    for (int i = 0; i < 4; ++i)
#pragma unroll
        for (int j = 0; j < 4; ++j) acc[i][j] = (f32x4)0.f;

    const int lrow = lane & 15;
    const int lk8 = (lane >> 4) * 8;

    for (int k0 = 0; k0 < K; k0 += 32) {
#pragma unroll
        for (int p = 0; p < 2; ++p) {
            const u16* asrc;
            if constexpr (GATHER) {
                int f = k0 + scol8;
                asrc = A + (f < 256 ? sb[p] + f : rb[p] + (f - 256));
            } else {
                asrc = A + abase[p] + k0 + scol8;
            }
            __builtin_amdgcn_global_load_lds(
                (const __attribute__((address_space(1))) unsigned int*)asrc,
                (__attribute__((address_space(3))) unsigned int*)(As + (p * 256 + wid * 64) * 8),
                16, 0, 0);
            const u16* bsrc = Wt + bbase[p] + k0 + scol8;
            __builtin_amdgcn_global_load_lds(
                (const __attribute__((address_space(1))) unsigned int*)bsrc,
                (__attribute__((address_space(3))) unsigned int*)(Bs + (p * 256 + wid * 64) * 8),
                16, 0, 0);
        }
        __syncthreads();
        bf16x8 a[4], b[4];
#pragma unroll
        for (int i = 0; i < 4; ++i)
            a[i] = *(const bf16x8*)&As[(wm * 64 + i * 16 + lrow) * 32 + lk8];
#pragma unroll
        for (int j = 0; j < 4; ++j)
            b[j] = *(const bf16x8*)&Bs[(wn * 64 + j * 16 + lrow) * 32 + lk8];
#pragma unroll
        for (int i = 0; i < 4; ++i)
#pragma unroll
            for (int j = 0; j < 4; ++j)
                acc[i][j] = __builtin_amdgcn_mfma_f32_16x16x32_bf16(a[i], b[j], acc[i][j], 0, 0, 0);
        __syncthreads();
    }

    float bv[4];
#pragma unroll
    for (int j = 0; j < 4; ++j) bv[j] = bias[n0 + wn * 64 + j * 16 + lrow];
#pragma unroll
    for (int i = 0; i < 4; ++i) {
#pragma unroll
        for (int j = 0; j < 4; ++j) {
            int col = n0 + wn * 64 + j * 16 + lrow;
#pragma unroll
            for (int r = 0; r < 4; ++r) {
                int row = m0 + wm * 64 + i * 16 + (lane >> 4) * 4 + r;
                float v = acc[i][j][r] + bv[j];
                if (ACT == 1) v = elu(v);
                if (ACT == 2) v = v > 0.f ? v : 0.f;
                out[(size_t)row * 256 + col] = f2bf(v);
            }
        }
    }
}

// -------------------- per-channel stats: sum & sumsq --------------------
__global__ __launch_bounds__(256) void stats_accum(const u16* __restrict__ h, int rows,
                                                   float* __restrict__ sums) {
    __shared__ float ls[512];
    int tid = threadIdx.x;
    ls[tid] = 0.f;
    ls[tid + 256] = 0.f;
    __syncthreads();
    int r0 = blockIdx.x * 64;
    int ch8 = (tid & 31) * 8;
    float s[8] = {0, 0, 0, 0, 0, 0, 0, 0}, q[8] = {0, 0, 0, 0, 0, 0, 0, 0};
#pragma unroll
    for (int i = 0; i < 8; ++i) {
        int row = r0 + (tid >> 5) + i * 8;
        u16x8 v = *(const u16x8*)(h + (size_t)row * 256 + ch8);
#pragma unroll
        for (int e = 0; e < 8; ++e) {
            float f = bf2f(v[e]);
            s[e] += f;
            q[e] += f * f;
        }
    }
#pragma unroll
    for (int e = 0; e < 8; ++e) {
        atomicAdd(&ls[ch8 + e], s[e]);
        atomicAdd(&ls[256 + ch8 + e], q[e]);
    }
    __syncthreads();
    atomicAdd(&sums[tid], ls[tid]);
    atomicAdd(&sums[256 + tid], ls[256 + tid]);
}

__global__ void stats_final(const float* __restrict__ sums, const float* __restrict__ g,
                            const float* __restrict__ be, float invR, float* __restrict__ scsh) {
    int c = threadIdx.x;
    float mu = sums[c] * invR;
    float var = sums[256 + c] * invR - mu * mu;
    float rs = rsqrtf(var + 1e-5f);
    float sc = g[c] * rs;
    scsh[c] = sc;
    scsh[256 + c] = be[c] - mu * sc;
}

// -------------------- elementwise affine (+optional relu) --------------------
template <bool RELU>
__global__ __launch_bounds__(256) void norm_affine(const u16* __restrict__ in,
                                                   const float* __restrict__ scsh,
                                                   u16* __restrict__ out, int n8) {
    int i = blockIdx.x * 256 + threadIdx.x;
    if (i >= n8) return;
    size_t base = (size_t)i * 8;
    int ch8 = (int)(base & 255);
    u16x8 v = *(const u16x8*)(in + base);
    u16x8 o;
#pragma unroll
    for (int e = 0; e < 8; ++e) {
        float f = bf2f(v[e]);
        f = scsh[ch8 + e] * f + scsh[256 + ch8 + e];
        if (RELU) f = f > 0.f ? f : 0.f;
        o[e] = f2bf(f);
    }
    *(u16x8*)(out + base) = o;
}

// -------------------- edge2node: incidence sum + affine(batchnorm)/9 ---------
__global__ __launch_bounds__(256) void edge2node(const u16* __restrict__ h2,
                                                 const float* __restrict__ scsh2,
                                                 u16* __restrict__ n1) {
    int tid = threadIdx.x;
    int row = blockIdx.x * 8 + (tid >> 5);      // node row
    int ch8 = (tid & 31) * 8;
    int t = row & 63;
    int bv = row >> 6;
    int v = bv % NV;
    int b = bv / NV;
    float acc[8] = {0, 0, 0, 0, 0, 0, 0, 0};
#pragma unroll
    for (int i = 0; i < 9; ++i) {
        int s = i + (i >= v ? 1 : 0);
        int e = s * 9 + (v < s ? v : v - 1);
        u16x8 vv = *(const u16x8*)(h2 + ((size_t)((b * NE + e) * TT + t)) * 256 + ch8);
#pragma unroll
        for (int k = 0; k < 8; ++k) acc[k] += bf2f(vv[k]);
    }
    const float inv9 = 1.f / 9.f;
    u16x8 o;
#pragma unroll
    for (int k = 0; k < 8; ++k) {
        int c = ch8 + k;
        o[k] = f2bf(scsh2[c] * (acc[k] * inv9) + scsh2[256 + c]);
    }
    *(u16x8*)(n1 + (size_t)row * 256 + ch8) = o;
}

// -------------------- final head: dot(a2_row, wo2) + bo2 --------------------
__global__ __launch_bounds__(256) void head2(const u16* __restrict__ a2,
                                             const u16* __restrict__ wo2t,
                                             const float* __restrict__ bo2,
                                             float* __restrict__ out) {
    int tid = threadIdx.x;
    int row = blockIdx.x * 8 + (tid >> 5);
    int l32 = tid & 31;
    int ch8 = l32 * 8;
    u16x8 a = *(const u16x8*)(a2 + (size_t)row * 256 + ch8);
    u16x8 w = *(const u16x8*)(wo2t + ch8);
    float p = 0.f;
#pragma unroll
    for (int k = 0; k < 8; ++k) p += bf2f(a[k]) * bf2f(w[k]);
#pragma unroll
    for (int off = 16; off > 0; off >>= 1) p += __shfl_down(p, off, 32);
    if (l32 == 0) {
        int b = row / (NV * TT);
        int v = (row >> 6) % NV;
        int t = row & 63;
        out[(size_t)(b * TT + t) * NV + v] = p + bo2[0];
    }
}

extern "C" void kernel_launch(void* const* d_in, const int* in_sizes, int n_in,
                              void* d_out, int out_size, void* d_ws, size_t ws_size,
                              hipStream_t stream) {
    const float* x   = (const float*)d_in[0];
    const float* w1a = (const float*)d_in[1];
    const float* b1a = (const float*)d_in[2];
    const float* w1b = (const float*)d_in[3];
    const float* b1b = (const float*)d_in[4];
    const float* g1  = (const float*)d_in[5];
    const float* be1 = (const float*)d_in[6];
    const float* w2a = (const float*)d_in[7];
    const float* b2a = (const float*)d_in[8];
    const float* w2b = (const float*)d_in[9];
    const float* b2b = (const float*)d_in[10];
    const float* g2  = (const float*)d_in[11];
    const float* be2 = (const float*)d_in[12];
    const float* w3a = (const float*)d_in[13];
    const float* b3a = (const float*)d_in[14];
    const float* w3b = (const float*)d_in[15];
    const float* g3w = (const float*)d_in[17];
    const float* b3b = (const float*)d_in[16];
    const float* be3 = (const float*)d_in[18];
    const float* wo1 = (const float*)d_in[19];
    const float* bo1 = (const float*)d_in[20];
    const float* wo2 = (const float*)d_in[21];
    const float* bo2 = (const float*)d_in[22];
    float* out = (float*)d_out;

    char* ws = (char*)d_ws;
    size_t off = 0;
    auto alloc = [&](size_t bytes) {
        void* p = ws + off;
        off = (off + bytes + 255) & ~(size_t)255;
        return p;
    };
    u16* w1aT = (u16*)alloc(256 * 4 * 2);
    u16* w1bT = (u16*)alloc(256 * 256 * 2);
    u16* w2aT = (u16*)alloc(256 * 512 * 2);
    u16* w2bT = (u16*)alloc(256 * 256 * 2);
    u16* w3aT = (u16*)alloc(256 * 256 * 2);
    u16* w3bT = (u16*)alloc(256 * 256 * 2);
    u16* wo1T = (u16*)alloc(256 * 256 * 2);
    u16* wo2T = (u16*)alloc(256 * 2);
    float* sums  = (float*)alloc(3 * 512 * 4);   // [sums1|sums2|sums3]
    float* scsh1 = (float*)alloc(512 * 4);
    float* scsh2 = (float*)alloc(512 * 4);
    float* scsh3 = (float*)alloc(512 * 4);
    u16* S0 = (u16*)alloc((size_t)R1 * 256 * 2);
    u16* S1 = (u16*)alloc((size_t)R1 * 256 * 2);
    u16* S2 = (u16*)alloc((size_t)R1 * 256 * 2);
    u16* BIG1 = (u16*)alloc((size_t)R2 * 256 * 2);
    u16* BIG2 = (u16*)alloc((size_t)R2 * 256 * 2);

    // weight conversion (tiny)
    transpose_w<<<4, 256, 0, stream>>>(w1a, w1aT, 4, 256);
    transpose_w<<<256, 256, 0, stream>>>(w1b, w1bT, 256, 256);
    transpose_w<<<512, 256, 0, stream>>>(w2a, w2aT, 512, 256);
    transpose_w<<<256, 256, 0, stream>>>(w2b, w2bT, 256, 256);
    transpose_w<<<256, 256, 0, stream>>>(w3a, w3aT, 256, 256);
    transpose_w<<<256, 256, 0, stream>>>(w3b, w3bT, 256, 256);
    transpose_w<<<256, 256, 0, stream>>>(wo1, wo1T, 256, 256);
    transpose_w<<<1, 256, 0, stream>>>(wo2, wo2T, 256, 1);
    zero_stats<<<6, 256, 0, stream>>>(sums, 3 * 512);

    // mlp1
    mlp1_fc1<<<R1 / 8, 256, 0, stream>>>(x, w1a, b1a, S0);
    gemm_kernel<false, 1><<<(R1 / 128) * 2, 256, 0, stream>>>(S0, w1bT, b1b, S1, 256);
    stats_accum<<<R1 / 64, 256, 0, stream>>>(S1, R1, sums);
    stats_final<<<1, 256, 0, stream>>>(sums, g1, be1, 1.f / R1, scsh1);
    norm_affine<false><<<(R1 * 32 + 255) / 256, 256, 0, stream>>>(S1, scsh1, S2, R1 * 32);

    // mlp2 (node2edge gather fused into fc1 staging)
    gemm_kernel<true, 1><<<(R2 / 128) * 2, 256, 0, stream>>>(S2, w2aT, b2a, BIG1, 512);
    gemm_kernel<false, 1><<<(R2 / 128) * 2, 256, 0, stream>>>(BIG1, w2bT, b2b, BIG2, 256);
    stats_accum<<<R2 / 64, 256, 0, stream>>>(BIG2, R2, sums + 512);
    stats_final<<<1, 256, 0, stream>>>(sums + 512, g2, be2, 1.f / R2, scsh2);

    // edge2node (batchnorm2 affine folded in)
    edge2node<<<R1 / 8, 256, 0, stream>>>(BIG2, scsh2, S0);

    // mlp3
    gemm_kernel<false, 1><<<(R1 / 128) * 2, 256, 0, stream>>>(S0, w3aT, b3a, S1, 256);
    gemm_kernel<false, 1><<<(R1 / 128) * 2, 256, 0, stream>>>(S1, w3bT, b3b, S2, 256);
    stats_accum<<<R1 / 64, 256, 0, stream>>>(S2, R1, sums + 1024);
    stats_final<<<1, 256, 0, stream>>>(sums + 1024, g3w, be3, 1.f / R1, scsh3);
    norm_affine<true><<<(R1 * 32 + 255) / 256, 256, 0, stream>>>(S2, scsh3, S0, R1 * 32);

    // head
    gemm_kernel<false, 2><<<(R1 / 128) * 2, 256, 0, stream>>>(S0, wo1T, bo1, S1, 256);
    head2<<<R1 / 8, 256, 0, stream>>>(S1, wo2T, bo2, out);
}